// Round 3
// baseline (837.430 us; speedup 1.0000x reference)
//
#include <hip/hip_runtime.h>
#include <hip/hip_bf16.h>

constexpr int kB   = 32;
constexpr int kC   = 256;
constexpr int kHW  = 4096;   // 64*64
constexpr int kC4  = 64;
constexpr int kGC  = 16;
constexpr int kNID = 80;     // 128 - 3*16

__device__ __forceinline__ float gelu_exact(float x) {
    return 0.5f * x * (1.0f + erff(x * 0.70710678118654752440f));
}

// float atomic max via sign-aware integer atomics (correct for mixed signs).
__device__ __forceinline__ void atomicMaxF(float* addr, float v) {
    int vi = __float_as_int(v);
    if (vi >= 0) atomicMax((int*)addr, vi);
    else         atomicMin((unsigned int*)addr, __float_as_uint(v));
}

// ---------------- Kernel 0: init pooled buffers (ws is poisoned 0xAA) ----------------
__global__ __launch_bounds__(256) void init_kernel(float* __restrict__ qp, float* __restrict__ kp)
{
    size_t i = (size_t)blockIdx.x * 256 + threadIdx.x;   // 32*64*1024 = 2,097,152 each
    qp[i] = 0.0f;
    kp[i] = -1e30f;
}

// ---------------- Kernel 1: x1 branch (identity + 3 depthwise convs) + GELU ----------------
__global__ __launch_bounds__(256) void part1_kernel(
    const float* __restrict__ x,
    const float* __restrict__ w_hw, const float* __restrict__ b_hw,
    const float* __restrict__ w_w,  const float* __restrict__ b_w,
    const float* __restrict__ w_h,  const float* __restrict__ b_h,
    float* __restrict__ out)
{
    int bc = blockIdx.x;            // b*128 + c
    int b  = bc >> 7;
    int c  = bc & 127;
    const float* xp = x   + (size_t)(b * kC + c) * kHW;
    float*       op = out + (size_t)(b * kC + c) * kHW;
    int tid = threadIdx.x;

    if (c < kNID) {
        for (int i = tid; i < kHW; i += 256)
            op[i] = gelu_exact(xp[i]);
    } else if (c < kNID + kGC) {           // 3x3 dwconv, pad 1
        int g = c - kNID;
        float wv[9];
        #pragma unroll
        for (int j = 0; j < 9; ++j) wv[j] = w_hw[g * 9 + j];
        float bias = b_hw[g];
        for (int i = tid; i < kHW; i += 256) {
            int h = i >> 6, w = i & 63;
            float acc = bias;
            #pragma unroll
            for (int dy = -1; dy <= 1; ++dy) {
                int hh = h + dy;
                if ((unsigned)hh >= 64u) continue;
                #pragma unroll
                for (int dx = -1; dx <= 1; ++dx) {
                    int ww = w + dx;
                    if ((unsigned)ww >= 64u) continue;
                    acc += wv[(dy + 1) * 3 + (dx + 1)] * xp[hh * 64 + ww];
                }
            }
            op[i] = gelu_exact(acc);
        }
    } else if (c < kNID + 2 * kGC) {       // 1x11 dwconv, pad (0,5)
        int g = c - (kNID + kGC);
        float wv[11];
        #pragma unroll
        for (int j = 0; j < 11; ++j) wv[j] = w_w[g * 11 + j];
        float bias = b_w[g];
        for (int i = tid; i < kHW; i += 256) {
            int h = i >> 6, w = i & 63;
            float acc = bias;
            #pragma unroll
            for (int j = 0; j < 11; ++j) {
                int ww = w + j - 5;
                if ((unsigned)ww < 64u) acc += wv[j] * xp[h * 64 + ww];
            }
            op[i] = gelu_exact(acc);
        }
    } else {                               // 11x1 dwconv, pad (5,0)
        int g = c - (kNID + 2 * kGC);
        float wv[11];
        #pragma unroll
        for (int j = 0; j < 11; ++j) wv[j] = w_h[g * 11 + j];
        float bias = b_h[g];
        for (int i = tid; i < kHW; i += 256) {
            int h = i >> 6, w = i & 63;
            float acc = bias;
            #pragma unroll
            for (int j = 0; j < 11; ++j) {
                int hh = h + j - 5;
                if ((unsigned)hh < 64u) acc += wv[j] * xp[hh * 64 + w];
            }
            op[i] = gelu_exact(acc);
        }
    }
}

// ---------------- Kernel 2: 1x1 conv (256x128 GEMM over pixels) + GELU + fused pooling ----------------
// Grid: (64 rows, 4 heads, B). Block 256 = 16(out-groups) x 16(pix-groups), 4x4 acc/thread.
// One pixel tile (64 consecutive pixels) == one image row h = blockIdx.x.
// v (head 2) goes fp32 into out channels 192..255 (overwritten later by out2).
__global__ __launch_bounds__(256) void conv1x1_kernel(
    const float* __restrict__ x,
    const float* __restrict__ w_qkvl, const float* __restrict__ b_qkvl,
    float* __restrict__ qp, float* __restrict__ kp,
    float* __restrict__ out)
{
    __shared__ float Ws[64][65];   // [k][o] +1 pad
    __shared__ float Xs[64][64];   // [k][p]
    int p0 = blockIdx.x * 64;
    int o0 = blockIdx.y * 64;
    int head = blockIdx.y;
    int b  = blockIdx.z;
    int t  = threadIdx.x;
    int to = t >> 4, tp = t & 15;

    float acc[4][4] = {};
    for (int kc = 0; kc < 2; ++kc) {
        #pragma unroll
        for (int r = 0; r < 16; ++r) {       // stage W tile (coalesced in k)
            int g = t + r * 256;
            int o = g >> 6, k = g & 63;
            Ws[k][o] = w_qkvl[(o0 + o) * 128 + kc * 64 + k];
        }
        #pragma unroll
        for (int r = 0; r < 16; ++r) {       // stage X tile (coalesced in p)
            int g = t + r * 256;
            int k = g >> 6, p = g & 63;
            Xs[k][p] = x[(size_t)(b * kC + 128 + kc * 64 + k) * kHW + p0 + p];
        }
        __syncthreads();
        #pragma unroll
        for (int k = 0; k < 64; ++k) {
            float xv[4], wv[4];
            #pragma unroll
            for (int j = 0; j < 4; ++j) xv[j] = Xs[k][tp * 4 + j];
            #pragma unroll
            for (int i = 0; i < 4; ++i) wv[i] = Ws[k][to * 4 + i];
            #pragma unroll
            for (int i = 0; i < 4; ++i)
                #pragma unroll
                for (int j = 0; j < 4; ++j)
                    acc[i][j] += wv[i] * xv[j];
        }
        __syncthreads();
    }

    // epilogue: bias + gelu, route by head (wave-uniform head == blockIdx.y)
    int h = blockIdx.x;           // image row
    int my = h >> 1;
    bool ey = (h & 1) && (my + 1 < 32);   // odd rows feed two avg-pool rows
    #pragma unroll
    for (int i = 0; i < 4; ++i) {
        int o = o0 + to * 4 + i;
        float bias = b_qkvl[o];
        int ch = o & 63;
        #pragma unroll
        for (int j = 0; j < 4; ++j) {
            float y = gelu_exact(acc[i][j] + bias);
            int p = p0 + tp * 4 + j;
            int wcol = p & 63;
            if (head == 0) {               // q -> fused 3x3 s2 p1 avg-pool (atomicAdd of y/9)
                float contrib = y * (1.0f / 9.0f);
                int mx = wcol >> 1;
                bool ex = (wcol & 1) && (mx + 1 < 32);
                size_t basep = ((size_t)(b * kC4 + ch)) << 10;   // *1024
                atomicAdd(&qp[basep + my * 32 + mx], contrib);
                if (ex) atomicAdd(&qp[basep + my * 32 + mx + 1], contrib);
                if (ey) atomicAdd(&qp[basep + (my + 1) * 32 + mx], contrib);
                if (ey && ex) atomicAdd(&qp[basep + (my + 1) * 32 + mx + 1], contrib);
            } else if (head == 1) {        // k -> fused 2x2 s2 max-pool
                size_t basep = ((size_t)(b * kC4 + ch)) << 10;
                atomicMaxF(&kp[basep + (h >> 1) * 32 + (wcol >> 1)], y);
            } else if (head == 2) {        // v -> out channels 192..255 (temp storage)
                out[(size_t)(b * kC + 192 + ch) * kHW + p] = y;
            } else {                       // lfeat -> out channels 128..191
                out[(size_t)(b * kC + 128 + ch) * kHW + p] = y;
            }
        }
    }
}

// ---------------- Kernel 3: qk = qf @ kf^T (sum over 1024), softmax over c ----------------
// Grid: (4 d-tiles, B). Block: thread t -> c = t&63, d-group = t>>6 (4 d's each).
__global__ __launch_bounds__(256) void qk_softmax_kernel(
    const float* __restrict__ qp, const float* __restrict__ kp,
    float* __restrict__ attn)
{
    __shared__ float qs[64][129];
    __shared__ float ks[16][129];
    __shared__ float qk_s[64][17];
    __shared__ float mx[16], sm[16];
    int dt = blockIdx.x;
    int b  = blockIdx.y;
    int t  = threadIdx.x;
    int c  = t & 63, dg = t >> 6;

    float acc[4] = {};
    for (int nc = 0; nc < 8; ++nc) {
        #pragma unroll
        for (int r = 0; r < 32; ++r) {
            int g = t + r * 256;
            int cc = g >> 7, n = g & 127;
            qs[cc][n] = qp[(size_t)(b * 64 + cc) * 1024 + nc * 128 + n];
        }
        #pragma unroll
        for (int r = 0; r < 8; ++r) {
            int g = t + r * 256;
            int dl = g >> 7, n = g & 127;
            ks[dl][n] = kp[(size_t)(b * 64 + dt * 16 + dl) * 1024 + nc * 128 + n];
        }
        __syncthreads();
        for (int n = 0; n < 128; ++n) {
            float qv = qs[c][n];
            #pragma unroll
            for (int j = 0; j < 4; ++j)
                acc[j] += qv * ks[dg * 4 + j][n];
        }
        __syncthreads();
    }
    #pragma unroll
    for (int j = 0; j < 4; ++j) qk_s[c][dg * 4 + j] = acc[j];
    __syncthreads();
    if (t < 16) {
        float m = -1e30f;
        for (int cc = 0; cc < 64; ++cc) m = fmaxf(m, qk_s[cc][t]);
        float s = 0.f;
        for (int cc = 0; cc < 64; ++cc) s += expf(qk_s[cc][t] - m);
        mx[t] = m;
        sm[t] = 1.0f / s;
    }
    __syncthreads();
    #pragma unroll
    for (int j = 0; j < 4; ++j) {
        int d = dg * 4 + j;
        attn[(size_t)(b * 64 + c) * 64 + dt * 16 + d] = expf(acc[j] - mx[d]) * sm[d];
    }
}

// ---------------- Kernel 4: out[b,192+d,m] = sum_c attn[b,c,d] * v[b,c,m] ----------------
// v lives in out channels 192..255 (written by conv1x1). Each thread owns one
// pixel column m: reads all 64 v values into registers, then overwrites the
// same 64 cells — no cross-thread aliasing, read-before-write per thread.
__global__ __launch_bounds__(256) void out2_kernel(
    const float* __restrict__ attn, float* __restrict__ out)
{
    __shared__ float at[64][64];   // [c][d]
    int b = blockIdx.y;
    int t = threadIdx.x;
    #pragma unroll
    for (int r = 0; r < 16; ++r) {
        int g = t + r * 256;
        at[g >> 6][g & 63] = attn[(size_t)b * 4096 + g];
    }
    __syncthreads();
    int m = blockIdx.x * 256 + t;
    float* vcol = out + (size_t)(b * kC + 192) * kHW + m;   // stride kHW per channel
    float vreg[64];
    #pragma unroll
    for (int cc = 0; cc < 64; ++cc) vreg[cc] = vcol[(size_t)cc * kHW];
    float acc[64] = {};
    for (int cc = 0; cc < 64; ++cc) {
        float vv = vreg[cc];
        #pragma unroll
        for (int d4 = 0; d4 < 16; ++d4) {
            float4 a = *(const float4*)&at[cc][d4 * 4];
            acc[d4 * 4 + 0] += a.x * vv;
            acc[d4 * 4 + 1] += a.y * vv;
            acc[d4 * 4 + 2] += a.z * vv;
            acc[d4 * 4 + 3] += a.w * vv;
        }
    }
    #pragma unroll
    for (int d = 0; d < 64; ++d)
        vcol[(size_t)d * kHW] = acc[d];
}

extern "C" void kernel_launch(void* const* d_in, const int* in_sizes, int n_in,
                              void* d_out, int out_size, void* d_ws, size_t ws_size,
                              hipStream_t stream)
{
    const float* x      = (const float*)d_in[0];
    const float* w_hw   = (const float*)d_in[1];
    const float* b_hw   = (const float*)d_in[2];
    const float* w_w    = (const float*)d_in[3];
    const float* b_w    = (const float*)d_in[4];
    const float* w_h    = (const float*)d_in[5];
    const float* b_h    = (const float*)d_in[6];
    const float* w_qkvl = (const float*)d_in[7];
    const float* b_qkvl = (const float*)d_in[8];
    float* out = (float*)d_out;

    // Workspace layout (~17.3 MB): qp fp32 | kp fp32 | attn fp32
    char* w = (char*)d_ws;
    float* qp   = (float*)w;  w += (size_t)kB * kC4 * 1024 * 4;   // 8.39 MB
    float* kp   = (float*)w;  w += (size_t)kB * kC4 * 1024 * 4;   // 8.39 MB
    float* attn = (float*)w;  w += (size_t)kB * kC4 * kC4 * 4;    // 0.52 MB

    init_kernel<<<dim3(8192), 256, 0, stream>>>(qp, kp);
    part1_kernel<<<dim3(kB * 128), 256, 0, stream>>>(x, w_hw, b_hw, w_w, b_w, w_h, b_h, out);
    conv1x1_kernel<<<dim3(64, 4, kB), 256, 0, stream>>>(x, w_qkvl, b_qkvl, qp, kp, out);
    qk_softmax_kernel<<<dim3(4, kB), 256, 0, stream>>>(qp, kp, attn);
    out2_kernel<<<dim3(16, kB), 256, 0, stream>>>(attn, out);
}

// Round 4
// 754.356 us; speedup vs baseline: 1.1101x; 1.1101x over previous
//
#include <hip/hip_runtime.h>
#include <hip/hip_bf16.h>

constexpr int kB   = 32;
constexpr int kC   = 256;
constexpr int kHW  = 4096;   // 64*64
constexpr int kC4  = 64;
constexpr int kGC  = 16;
constexpr int kNID = 80;     // 128 - 3*16

__device__ __forceinline__ float gelu_exact(float x) {
    return 0.5f * x * (1.0f + erff(x * 0.70710678118654752440f));
}

// float atomic max via sign-aware integer atomics (correct for mixed signs).
__device__ __forceinline__ void atomicMaxF(float* addr, float v) {
    int vi = __float_as_int(v);
    if (vi >= 0) atomicMax((int*)addr, vi);
    else         atomicMin((unsigned int*)addr, __float_as_uint(v));
}

// ---------------- Kernel 0: init pooled buffers (ws is poisoned 0xAA) ----------------
__global__ __launch_bounds__(256) void init_kernel(float* __restrict__ qp, float* __restrict__ kp)
{
    size_t i = (size_t)blockIdx.x * 256 + threadIdx.x;   // 32*64*1024 = 2,097,152 each
    qp[i] = 0.0f;
    kp[i] = -1e30f;
}

// ---------------- Kernel 1: x1 branch (identity + 3 depthwise convs) + GELU ----------------
__global__ __launch_bounds__(256) void part1_kernel(
    const float* __restrict__ x,
    const float* __restrict__ w_hw, const float* __restrict__ b_hw,
    const float* __restrict__ w_w,  const float* __restrict__ b_w,
    const float* __restrict__ w_h,  const float* __restrict__ b_h,
    float* __restrict__ out)
{
    int bc = blockIdx.x;            // b*128 + c
    int b  = bc >> 7;
    int c  = bc & 127;
    const float* xp = x   + (size_t)(b * kC + c) * kHW;
    float*       op = out + (size_t)(b * kC + c) * kHW;
    int tid = threadIdx.x;

    if (c < kNID) {
        for (int i = tid; i < kHW; i += 256)
            op[i] = gelu_exact(xp[i]);
    } else if (c < kNID + kGC) {           // 3x3 dwconv, pad 1
        int g = c - kNID;
        float wv[9];
        #pragma unroll
        for (int j = 0; j < 9; ++j) wv[j] = w_hw[g * 9 + j];
        float bias = b_hw[g];
        for (int i = tid; i < kHW; i += 256) {
            int h = i >> 6, w = i & 63;
            float acc = bias;
            #pragma unroll
            for (int dy = -1; dy <= 1; ++dy) {
                int hh = h + dy;
                if ((unsigned)hh >= 64u) continue;
                #pragma unroll
                for (int dx = -1; dx <= 1; ++dx) {
                    int ww = w + dx;
                    if ((unsigned)ww >= 64u) continue;
                    acc += wv[(dy + 1) * 3 + (dx + 1)] * xp[hh * 64 + ww];
                }
            }
            op[i] = gelu_exact(acc);
        }
    } else if (c < kNID + 2 * kGC) {       // 1x11 dwconv, pad (0,5)
        int g = c - (kNID + kGC);
        float wv[11];
        #pragma unroll
        for (int j = 0; j < 11; ++j) wv[j] = w_w[g * 11 + j];
        float bias = b_w[g];
        for (int i = tid; i < kHW; i += 256) {
            int h = i >> 6, w = i & 63;
            float acc = bias;
            #pragma unroll
            for (int j = 0; j < 11; ++j) {
                int ww = w + j - 5;
                if ((unsigned)ww < 64u) acc += wv[j] * xp[h * 64 + ww];
            }
            op[i] = gelu_exact(acc);
        }
    } else {                               // 11x1 dwconv, pad (5,0)
        int g = c - (kNID + 2 * kGC);
        float wv[11];
        #pragma unroll
        for (int j = 0; j < 11; ++j) wv[j] = w_h[g * 11 + j];
        float bias = b_h[g];
        for (int i = tid; i < kHW; i += 256) {
            int h = i >> 6, w = i & 63;
            float acc = bias;
            #pragma unroll
            for (int j = 0; j < 11; ++j) {
                int hh = h + j - 5;
                if ((unsigned)hh < 64u) acc += wv[j] * xp[hh * 64 + w];
            }
            op[i] = gelu_exact(acc);
        }
    }
}

// ---------------- Kernel 2: 1x1 conv GEMM + GELU + LDS-reduced pooling ----------------
// Grid: (64 rows, 4 heads, B). Block 256 = 16(out-groups) x 16(pix-groups), 4x4 acc/thread.
// Heads 0/1 stage GELU outputs in LDS (reusing Xs), reduce the horizontal pool
// in-block, then issue ONE distinct-address atomic per (ch, pool-col) cell
// (8-16 per thread) instead of <=64 same-address-conflicting atomics per thread.
__global__ __launch_bounds__(256) void conv1x1_kernel(
    const float* __restrict__ x,
    const float* __restrict__ w_qkvl, const float* __restrict__ b_qkvl,
    float* __restrict__ qp, float* __restrict__ kp,
    float* __restrict__ out)
{
    __shared__ float Ws[64][65];   // [k][o] +1 pad
    __shared__ float Xs[64][64];   // [k][p]; reused as Ys[ch][col] in epilogue
    int p0 = blockIdx.x * 64;
    int o0 = blockIdx.y * 64;
    int head = blockIdx.y;
    int b  = blockIdx.z;
    int t  = threadIdx.x;
    int to = t >> 4, tp = t & 15;

    float acc[4][4] = {};
    for (int kc = 0; kc < 2; ++kc) {
        #pragma unroll
        for (int r = 0; r < 16; ++r) {       // stage W tile (coalesced in k)
            int g = t + r * 256;
            int o = g >> 6, k = g & 63;
            Ws[k][o] = w_qkvl[(o0 + o) * 128 + kc * 64 + k];
        }
        #pragma unroll
        for (int r = 0; r < 16; ++r) {       // stage X tile (coalesced in p)
            int g = t + r * 256;
            int k = g >> 6, p = g & 63;
            Xs[k][p] = x[(size_t)(b * kC + 128 + kc * 64 + k) * kHW + p0 + p];
        }
        __syncthreads();
        #pragma unroll
        for (int k = 0; k < 64; ++k) {
            float xv[4], wv[4];
            #pragma unroll
            for (int j = 0; j < 4; ++j) xv[j] = Xs[k][tp * 4 + j];
            #pragma unroll
            for (int i = 0; i < 4; ++i) wv[i] = Ws[k][to * 4 + i];
            #pragma unroll
            for (int i = 0; i < 4; ++i)
                #pragma unroll
                for (int j = 0; j < 4; ++j)
                    acc[i][j] += wv[i] * xv[j];
        }
        __syncthreads();
    }

    int h = blockIdx.x;           // image row
    if (head < 2) {
        // stage bias+gelu outputs: Ys[ch][col]  (Xs reuse; last loop iter ended with syncthreads)
        #pragma unroll
        for (int i = 0; i < 4; ++i) {
            int o = to * 4 + i;
            float bias = b_qkvl[o0 + o];
            float4 v;
            v.x = gelu_exact(acc[i][0] + bias);
            v.y = gelu_exact(acc[i][1] + bias);
            v.z = gelu_exact(acc[i][2] + bias);
            v.w = gelu_exact(acc[i][3] + bias);
            *(float4*)&Xs[o][tp * 4] = v;
        }
        __syncthreads();
        if (head == 0) {           // q: 3x3 s2 p1 avg-pool; horizontal in-block, vertical via atomics
            int my = h >> 1;
            bool ey = (h & 1) && (my + 1 < 32);   // odd rows feed two pool rows
            for (int e = t; e < 2048; e += 256) {
                int ch = e >> 5, mx = e & 31;
                float s = Xs[ch][2 * mx] + Xs[ch][2 * mx + 1];
                if (mx > 0) s += Xs[ch][2 * mx - 1];
                s *= (1.0f / 9.0f);
                float* dst = &qp[(((size_t)(b * kC4 + ch)) << 10) + my * 32 + mx];
                atomicAdd(dst, s);
                if (ey) atomicAdd(dst + 32, s);
            }
        } else {                   // k: 2x2 s2 max-pool; horizontal in-block, vertical via atomicMax
            for (int e = t; e < 2048; e += 256) {
                int ch = e >> 5, mx = e & 31;
                float m = fmaxf(Xs[ch][2 * mx], Xs[ch][2 * mx + 1]);
                atomicMaxF(&kp[(((size_t)(b * kC4 + ch)) << 10) + (h >> 1) * 32 + mx], m);
            }
        }
    } else {
        // v -> out ch 192..255 (temp storage), lfeat -> out ch 128..191
        int cbase = (head == 2) ? 192 : 128;
        #pragma unroll
        for (int i = 0; i < 4; ++i) {
            int o = to * 4 + i;
            float bias = b_qkvl[o0 + o];
            #pragma unroll
            for (int j = 0; j < 4; ++j) {
                float y = gelu_exact(acc[i][j] + bias);
                int p = p0 + tp * 4 + j;
                out[(size_t)(b * kC + cbase + o) * kHW + p] = y;
            }
        }
    }
}

// ---------------- Kernel 3: qk = qf @ kf^T (sum over 1024), softmax over c ----------------
__global__ __launch_bounds__(256) void qk_softmax_kernel(
    const float* __restrict__ qp, const float* __restrict__ kp,
    float* __restrict__ attn)
{
    __shared__ float qs[64][129];
    __shared__ float ks[16][129];
    __shared__ float qk_s[64][17];
    __shared__ float mx[16], sm[16];
    int dt = blockIdx.x;
    int b  = blockIdx.y;
    int t  = threadIdx.x;
    int c  = t & 63, dg = t >> 6;

    float acc[4] = {};
    for (int nc = 0; nc < 8; ++nc) {
        #pragma unroll
        for (int r = 0; r < 32; ++r) {
            int g = t + r * 256;
            int cc = g >> 7, n = g & 127;
            qs[cc][n] = qp[(size_t)(b * 64 + cc) * 1024 + nc * 128 + n];
        }
        #pragma unroll
        for (int r = 0; r < 8; ++r) {
            int g = t + r * 256;
            int dl = g >> 7, n = g & 127;
            ks[dl][n] = kp[(size_t)(b * 64 + dt * 16 + dl) * 1024 + nc * 128 + n];
        }
        __syncthreads();
        for (int n = 0; n < 128; ++n) {
            float qv = qs[c][n];
            #pragma unroll
            for (int j = 0; j < 4; ++j)
                acc[j] += qv * ks[dg * 4 + j][n];
        }
        __syncthreads();
    }
    #pragma unroll
    for (int j = 0; j < 4; ++j) qk_s[c][dg * 4 + j] = acc[j];
    __syncthreads();
    if (t < 16) {
        float m = -1e30f;
        for (int cc = 0; cc < 64; ++cc) m = fmaxf(m, qk_s[cc][t]);
        float s = 0.f;
        for (int cc = 0; cc < 64; ++cc) s += expf(qk_s[cc][t] - m);
        mx[t] = m;
        sm[t] = 1.0f / s;
    }
    __syncthreads();
    #pragma unroll
    for (int j = 0; j < 4; ++j) {
        int d = dg * 4 + j;
        attn[(size_t)(b * 64 + c) * 64 + dt * 16 + d] = expf(acc[j] - mx[d]) * sm[d];
    }
}

// ---------------- Kernel 4: out[b,192+d,m] = sum_c attn[b,c,d] * v[b,c,m] ----------------
// v lives in out channels 192..255; per-thread read-before-write, no aliasing.
__global__ __launch_bounds__(256) void out2_kernel(
    const float* __restrict__ attn, float* __restrict__ out)
{
    __shared__ float at[64][64];   // [c][d]
    int b = blockIdx.y;
    int t = threadIdx.x;
    #pragma unroll
    for (int r = 0; r < 16; ++r) {
        int g = t + r * 256;
        at[g >> 6][g & 63] = attn[(size_t)b * 4096 + g];
    }
    __syncthreads();
    int m = blockIdx.x * 256 + t;
    float* vcol = out + (size_t)(b * kC + 192) * kHW + m;   // stride kHW per channel
    float vreg[64];
    #pragma unroll
    for (int cc = 0; cc < 64; ++cc) vreg[cc] = vcol[(size_t)cc * kHW];
    float acc[64] = {};
    for (int cc = 0; cc < 64; ++cc) {
        float vv = vreg[cc];
        #pragma unroll
        for (int d4 = 0; d4 < 16; ++d4) {
            float4 a = *(const float4*)&at[cc][d4 * 4];
            acc[d4 * 4 + 0] += a.x * vv;
            acc[d4 * 4 + 1] += a.y * vv;
            acc[d4 * 4 + 2] += a.z * vv;
            acc[d4 * 4 + 3] += a.w * vv;
        }
    }
    #pragma unroll
    for (int d = 0; d < 64; ++d)
        vcol[(size_t)d * kHW] = acc[d];
}

extern "C" void kernel_launch(void* const* d_in, const int* in_sizes, int n_in,
                              void* d_out, int out_size, void* d_ws, size_t ws_size,
                              hipStream_t stream)
{
    const float* x      = (const float*)d_in[0];
    const float* w_hw   = (const float*)d_in[1];
    const float* b_hw   = (const float*)d_in[2];
    const float* w_w    = (const float*)d_in[3];
    const float* b_w    = (const float*)d_in[4];
    const float* w_h    = (const float*)d_in[5];
    const float* b_h    = (const float*)d_in[6];
    const float* w_qkvl = (const float*)d_in[7];
    const float* b_qkvl = (const float*)d_in[8];
    float* out = (float*)d_out;

    // Workspace layout (~17.3 MB): qp fp32 | kp fp32 | attn fp32
    char* w = (char*)d_ws;
    float* qp   = (float*)w;  w += (size_t)kB * kC4 * 1024 * 4;   // 8.39 MB
    float* kp   = (float*)w;  w += (size_t)kB * kC4 * 1024 * 4;   // 8.39 MB
    float* attn = (float*)w;  w += (size_t)kB * kC4 * kC4 * 4;    // 0.52 MB

    init_kernel<<<dim3(8192), 256, 0, stream>>>(qp, kp);
    part1_kernel<<<dim3(kB * 128), 256, 0, stream>>>(x, w_hw, b_hw, w_w, b_w, w_h, b_h, out);
    conv1x1_kernel<<<dim3(64, 4, kB), 256, 0, stream>>>(x, w_qkvl, b_qkvl, qp, kp, out);
    qk_softmax_kernel<<<dim3(4, kB), 256, 0, stream>>>(qp, kp, attn);
    out2_kernel<<<dim3(16, kB), 256, 0, stream>>>(attn, out);
}